// Round 12
// baseline (627.917 us; speedup 1.0000x reference)
//
#include <hip/hip_runtime.h>
#include <stdint.h>
#include <stddef.h>

// RRT/Nystrom attention, MI355X gfx950.
// Inputs/outputs FLOAT32. Heavy GEMMs: bf16 MFMA + fp32 accumulate,
// staged via global_load_lds(16B) with XOR chunk-swizzle (rule #21:
// linear LDS dest + inverse-swizzled global source + swizzled read).
// k_gemm_big blocks are XCD-chunked and A-panel-major (FETCH 117->31MB).
// Moore-Penrose chain: hi/lo bf16 planes split ONCE by each producer
// (fp32-grade via 3-plane MFMA). All chain matrices are symmetric
// (polynomials of A0 = s*attn2@attn2^T) -> B^T-rows = rows of same plane.
// Chain: DISCRETE launches, 32x64 tiles (measured optimal; in-kernel
// cross-WG sync costs 42-140us/barrier vs ~7us kernel boundary).
// LAUNCH-COUNT REDUCTION: independent DAG siblings block-partition-fused.
// ALIAS DISCIPLINE: convb ALIASES O_s -> conv runs strictly AFTER
// t2combine reads O_s. Fusion schedule:
//   F1 = cvt + W-transposes; F2 = v-transpose + landmarks;
//   F3 = attn3 + z0t + A0;  F4 = W2_0 + t2combine;  F5 = W3_0 + conv.
// THIS ROUND: (a) attn3 prefetches next iteration's K fragments right
// after the QK MFMAs (exp+PV hides the load latency); (b) z0 is an
// LDS-tiled 64x64 transpose with bf16x8 vector loads (was stride-512B
// scalar reads). Zero numerics change.
// Softmaxes WITHOUT max-subtraction: scores O(1) by construction.
// attn1/attn3: swapped-QK^T keeps P-rows lane-local; PV A-frag built
// in-register via k-slot permutation; zt2t stored pre-permuted.

typedef __bf16 bf16x8 __attribute__((ext_vector_type(8)));
typedef __bf16 bf16x4 __attribute__((ext_vector_type(4)));
typedef float f32x4 __attribute__((ext_vector_type(4)));

__device__ __forceinline__ f32x4 mfma_bf16(bf16x8 a, bf16x8 b, f32x4 c) {
    return __builtin_amdgcn_mfma_f32_16x16x32_bf16(a, b, c, 0, 0, 0);
}

__device__ __forceinline__ void gload16(const __bf16* g, __bf16* l) {
    __builtin_amdgcn_global_load_lds(
        (const __attribute__((address_space(1))) void*)g,
        (__attribute__((address_space(3))) void*)l, 16, 0, 0);
}

// ================= device bodies =================

// ---- x f32 -> bf16 ----
__device__ __forceinline__ void cvt_body(int bid, const float* __restrict__ in,
        __bf16* __restrict__ out) {
    size_t base = ((size_t)bid * 256 + threadIdx.x) * 8;
    float4 a = *(const float4*)&in[base];
    float4 b = *(const float4*)&in[base + 4];
    bf16x8 o;
    o[0] = (__bf16)a.x; o[1] = (__bf16)a.y; o[2] = (__bf16)a.z; o[3] = (__bf16)a.w;
    o[4] = (__bf16)b.x; o[5] = (__bf16)b.y; o[6] = (__bf16)b.z; o[7] = (__bf16)b.w;
    *(bf16x8*)&out[base] = o;
}

// ---- f32 -> bf16 transposed copy (weights), 64x64 tile ----
__device__ __forceinline__ void tf32_body(const float* __restrict__ in,
        __bf16* __restrict__ out, int R, int C, int bx, int by, __bf16* tile) {
    int r0 = bx * 64, c0 = by * 64;
    int tid = threadIdx.x;
    #pragma unroll
    for (int i = 0; i < 16; ++i) {
        int slot = i * 256 + tid;
        int rr = slot >> 6, cc = slot & 63;
        tile[rr * 72 + cc] = (__bf16)in[(size_t)(r0 + rr) * C + c0 + cc];
    }
    __syncthreads();
    #pragma unroll
    for (int i = 0; i < 2; ++i) {
        int slot = i * 256 + tid;
        int cc = slot >> 3, s = slot & 7;
        bf16x8 t;
        #pragma unroll
        for (int j = 0; j < 8; ++j) t[j] = tile[(s * 8 + j) * 72 + cc];
        *(bf16x8*)&out[(size_t)(c0 + cc) * R + r0 + s * 8] = t;
    }
}

// ---- bf16 transpose 64x64 (v -> vt), batch bz ----
__device__ __forceinline__ void tbf_body(const __bf16* __restrict__ in0,
        __bf16* __restrict__ out0, int bx, int bz, __bf16* tile) {
    const __bf16* in = in0 + (size_t)bz * 524288;
    __bf16* out = out0 + (size_t)bz * 524288;
    int r0 = bx * 64, c0 = 0;               // R=8192, C=64
    int tid = threadIdx.x;
    #pragma unroll
    for (int i = 0; i < 2; ++i) {
        int slot = i * 256 + tid;
        int rr = slot >> 3, s = slot & 7;
        *(bf16x8*)&tile[rr * 72 + s * 8] =
            *(const bf16x8*)&in[(size_t)(r0 + rr) * 64 + c0 + s * 8];
    }
    __syncthreads();
    #pragma unroll
    for (int i = 0; i < 2; ++i) {
        int slot = i * 256 + tid;
        int cc = slot >> 3, s = slot & 7;
        bf16x8 t;
        #pragma unroll
        for (int j = 0; j < 8; ++j) t[j] = tile[(s * 8 + j) * 72 + cc];
        *(bf16x8*)&out[(size_t)(c0 + cc) * 8192 + r0 + s * 8] = t;
    }
}

// ---- landmark means ----
__device__ __forceinline__ void landmarks_body(int idx, const __bf16* __restrict__ q,
        const __bf16* __restrict__ k, __bf16* __restrict__ ql, __bf16* __restrict__ kl) {
    int sel = idx >> 19;
    int rem = idx & 524287;
    int bh = rem >> 14;
    int m  = (rem >> 6) & 255;
    int d  = rem & 63;
    const __bf16* src = sel ? k : q;
    __bf16* dst = sel ? kl : ql;
    const __bf16* p = src + ((size_t)(bh * 8192 + m * 32)) * 64 + d;
    float s = 0.f;
    #pragma unroll
    for (int j = 0; j < 32; ++j) s += (float)p[j * 64];
    dst[(size_t)bh * 16384 + m * 64 + d] = (__bf16)(s * (1.f / 32.f));
}

// ---- z0 tile: z0 = attn2^T / colsum_max, hi/lo planes, 64x64 LDS transpose ----
__device__ __forceinline__ void z0t_body(int tileid, const __bf16* __restrict__ ph,
        const __bf16* __restrict__ pl, const float* __restrict__ stats,
        __bf16* __restrict__ zh, __bf16* __restrict__ zl,
        __bf16* th, __bf16* tl) {
    int bh = tileid >> 4;
    int r0 = ((tileid >> 2) & 3) * 64, c0 = (tileid & 3) * 64;
    const __bf16* ah = ph + (size_t)bh * 65536;
    const __bf16* al = pl + (size_t)bh * 65536;
    int tid = threadIdx.x;
    #pragma unroll
    for (int i = 0; i < 2; ++i) {
        int slot = i * 256 + tid;
        int rr = slot >> 3, s = slot & 7;   // a2 row c0+rr, cols r0+s*8..
        *(bf16x8*)&th[rr * 72 + s * 8] =
            *(const bf16x8*)&ah[(size_t)(c0 + rr) * 256 + r0 + s * 8];
        *(bf16x8*)&tl[rr * 72 + s * 8] =
            *(const bf16x8*)&al[(size_t)(c0 + rr) * 256 + r0 + s * 8];
    }
    __syncthreads();
    float inv = 1.f / (stats[0] * stats[1]);
    #pragma unroll
    for (int i = 0; i < 2; ++i) {
        int slot = i * 256 + tid;
        int cc = slot >> 3, s = slot & 7;   // out row r0+cc, cols c0+s*8..
        bf16x8 oh2, ol2;
        #pragma unroll
        for (int j = 0; j < 8; ++j) {
            float v = ((float)th[(s * 8 + j) * 72 + cc] +
                       (float)tl[(s * 8 + j) * 72 + cc]) * inv;
            __bf16 hh = (__bf16)v;
            oh2[j] = hh;
            ol2[j] = (__bf16)(v - (float)hh);
        }
        size_t di = ((size_t)bh << 16) + (size_t)(r0 + cc) * 256 + c0 + s * 8;
        *(bf16x8*)&zh[di] = oh2;
        *(bf16x8*)&zl[di] = ol2;
    }
}

// ---- plane GEMM core: 32x64 tile, K=256, LDS-staged, XOR swizzle ----
__device__ __forceinline__ void pgemm_core(const __bf16* __restrict__ Ah,
        const __bf16* __restrict__ Al, const __bf16* __restrict__ Bth,
        const __bf16* __restrict__ Btl, int m0, int n0,
        __bf16* sAh, __bf16* sAl, __bf16* sBh, __bf16* sBl, f32x4 acc[2]) {
    int tid = threadIdx.x;
    int wave = tid >> 6, l = tid & 63, lm = l & 15, lq = l >> 4;
    int wm = wave & 1, wn = wave >> 1;
    int lr = l >> 3, lc8 = l & 7;
    int src_c = (lc8 ^ lr) * 8;
    for (int k0 = 0; k0 < 256; k0 += 64) {
        {
            size_t ra = (size_t)(m0 + wave * 8 + lr) * 256 + k0 + src_c;
            gload16(&Ah[ra], &sAh[wave * 512]);
            gload16(&Al[ra], &sAl[wave * 512]);
        }
        #pragma unroll
        for (int i = 0; i < 2; ++i) {
            int g = wave * 2 + i;
            size_t rb = (size_t)(n0 + g * 8 + lr) * 256 + k0 + src_c;
            gload16(&Bth[rb], &sBh[g * 512]);
            gload16(&Btl[rb], &sBl[g * 512]);
        }
        __syncthreads();
        #pragma unroll
        for (int ko = 0; ko < 2; ++ko) {
            int ch = (ko << 2) | lq;
            int rA = wm * 16 + lm;
            int oA = rA * 64 + ((ch ^ (rA & 7)) << 3);
            bf16x8 a_h = *(bf16x8*)&sAh[oA];
            bf16x8 a_l = *(bf16x8*)&sAl[oA];
            bf16x8 b_h[2], b_l[2];
            #pragma unroll
            for (int ni = 0; ni < 2; ++ni) {
                int r = wn * 32 + ni * 16 + lm;
                int o = r * 64 + ((ch ^ (r & 7)) << 3);
                b_h[ni] = *(bf16x8*)&sBh[o];
                b_l[ni] = *(bf16x8*)&sBl[o];
            }
            #pragma unroll
            for (int ni = 0; ni < 2; ++ni) {
                acc[ni] = mfma_bf16(a_h, b_h[ni], acc[ni]);
                acc[ni] = mfma_bf16(a_h, b_l[ni], acc[ni]);
                acc[ni] = mfma_bf16(a_l, b_h[ni], acc[ni]);
            }
        }
        __syncthreads();
    }
}

// ---- one chain stage (32x64 tile); flat/total drive XCD-chunked remap ----
__device__ __forceinline__ void pgemm_stage(int flat, int total,
        const __bf16* __restrict__ Ah, const __bf16* __restrict__ Al,
        const __bf16* __restrict__ Bth, const __bf16* __restrict__ Btl,
        const __bf16* __restrict__ Ch, const __bf16* __restrict__ Cl,
        __bf16* __restrict__ OutH, __bf16* __restrict__ OutL,
        float aEff, float beta, float delta, int outMode, long bStride,
        __bf16* sAh, __bf16* sAl, __bf16* sBh, __bf16* sBl) {
    int tid = threadIdx.x;
    int wave = tid >> 6, l = tid & 63, lm = l & 15, lq = l >> 4;
    int wm = wave & 1, wn = wave >> 1;
    int t = (flat & 7) * (total >> 3) + (flat >> 3);
    int ntb = total >> 8;              // n-tiles per bh (4 or 1)
    int tpb = ntb << 3;                // tiles per bh
    int bh = t / tpb, rem = t - bh * tpb;
    int m0 = (rem / ntb) * 32, n0 = (rem % ntb) * 64;
    f32x4 acc[2] = {};
    pgemm_core(Ah + (size_t)bh * 65536, Al + (size_t)bh * 65536,
               Bth + (size_t)bh * bStride, Btl + (size_t)bh * bStride,
               m0, n0, sAh, sAl, sBh, sBl, acc);
    #pragma unroll
    for (int ni = 0; ni < 2; ++ni)
    #pragma unroll
    for (int reg = 0; reg < 4; ++reg) {
        int gr = m0 + wm * 16 + lq * 4 + reg;
        int gc = n0 + wn * 32 + ni * 16 + lm;
        float v = aEff * acc[ni][reg];
        if (beta != 0.f) {
            size_t ci = (size_t)bh * 65536 + (size_t)gr * 256 + gc;
            v += beta * ((float)Ch[ci] + (float)Cl[ci]);
        }
        if (gr == gc) v += delta;
        if (outMode == 0) {
            size_t di = (size_t)bh * 65536 + (size_t)gr * 256 + gc;
            __bf16 hh = (__bf16)v;
            OutH[di] = hh;
            OutL[di] = (__bf16)(v - (float)hh);
        } else {
            int ci2 = gr >> 4, lqm = (gr >> 2) & 3, r = gr & 3;
            int slot = ((ci2 >> 1) << 5) + (lqm << 3) + ((ci2 & 1) << 2) + r;
            OutH[(size_t)bh * 16384 + (size_t)gc * 256 + slot] = (__bf16)v;
        }
    }
}

// ---- attn3 flash body (swapped QK^T, P in-register, no LDS) ----
// K fragments for iteration it+1 are prefetched right after iteration it's
// QK MFMAs: the exp+PV phase hides the load latency.
__device__ __forceinline__ void attn3_body(int s, int bh,
        const __bf16* __restrict__ ql, const __bf16* __restrict__ kk,
        const __bf16* __restrict__ vt, float* __restrict__ O_s,
        float* __restrict__ l_s) {
    int tid = threadIdx.x;
    int wave = tid >> 6, l = tid & 63, lm = l & 15, lq = l >> 4;
    const __bf16* qb = ql + (size_t)bh * 16384;
    bf16x8 qa[4][2];
    #pragma unroll
    for (int mi = 0; mi < 4; ++mi)
        #pragma unroll
        for (int ko = 0; ko < 2; ++ko)
            qa[mi][ko] = *(const bf16x8*)&qb[(size_t)(wave * 64 + mi * 16 + lm) * 64 + ko * 32 + lq * 8];
    f32x4 O[4][4] = {};
    float lsum[4] = {};
    // preload K fragments for it=0
    bf16x8 kf[4][2];
    #pragma unroll
    for (int ci = 0; ci < 4; ++ci)
        #pragma unroll
        for (int ko = 0; ko < 2; ++ko)
            kf[ci][ko] = *(const bf16x8*)&kk[((size_t)bh * 8192 + s * 512 + ci * 16 + lm) * 64 + ko * 32 + lq * 8];
    for (int it = 0; it < 8; ++it) {
        int c0 = s * 512 + it * 64;
        f32x4 St[4][4] = {};
        #pragma unroll
        for (int ci = 0; ci < 4; ++ci)
            #pragma unroll
            for (int ko = 0; ko < 2; ++ko)
                #pragma unroll
                for (int mi = 0; mi < 4; ++mi)
                    St[mi][ci] = mfma_bf16(kf[ci][ko], qa[mi][ko], St[mi][ci]);
        // prefetch next iteration's K fragments (WAR after MFMAs above)
        if (it < 7) {
            int c1 = c0 + 64;
            #pragma unroll
            for (int ci = 0; ci < 4; ++ci)
                #pragma unroll
                for (int ko = 0; ko < 2; ++ko)
                    kf[ci][ko] = *(const bf16x8*)&kk[((size_t)bh * 8192 + c1 + ci * 16 + lm) * 64 + ko * 32 + lq * 8];
        }
        bf16x4 pk[4][4];
        #pragma unroll
        for (int mi = 0; mi < 4; ++mi)
            #pragma unroll
            for (int ci = 0; ci < 4; ++ci)
                #pragma unroll
                for (int reg = 0; reg < 4; ++reg) {
                    float e = __expf(St[mi][ci][reg]);
                    lsum[mi] += e;
                    pk[mi][ci][reg] = (__bf16)e;
                }
        #pragma unroll
        for (int ko = 0; ko < 2; ++ko) {
            bf16x8 af[4];
            #pragma unroll
            for (int mi = 0; mi < 4; ++mi)
                #pragma unroll
                for (int r = 0; r < 4; ++r) {
                    af[mi][r]     = pk[mi][2 * ko][r];
                    af[mi][4 + r] = pk[mi][2 * ko + 1][r];
                }
            #pragma unroll
            for (int ni = 0; ni < 4; ++ni) {
                const __bf16* vrow = &vt[((size_t)bh * 64 + ni * 16 + lm) * 8192 + c0 + ko * 32 + lq * 4];
                bf16x4 v0 = *(const bf16x4*)&vrow[0];
                bf16x4 v1 = *(const bf16x4*)&vrow[16];
                bf16x8 vb;
                #pragma unroll
                for (int r = 0; r < 4; ++r) { vb[r] = v0[r]; vb[4 + r] = v1[r]; }
                #pragma unroll
                for (int mi = 0; mi < 4; ++mi)
                    O[mi][ni] = mfma_bf16(af[mi], vb, O[mi][ni]);
            }
        }
    }
    #pragma unroll
    for (int mi = 0; mi < 4; ++mi) {
        float v = lsum[mi];
        v += __shfl_xor(v, 16);
        v += __shfl_xor(v, 32);
        lsum[mi] = v;
    }
    int base = (bh * 16 + s) * 256;
    #pragma unroll
    for (int mi = 0; mi < 4; ++mi)
        if (lq == 0) l_s[base + wave * 64 + mi * 16 + lm] = lsum[mi];
    #pragma unroll
    for (int mi = 0; mi < 4; ++mi)
        #pragma unroll
        for (int reg = 0; reg < 4; ++reg) {
            int r = wave * 64 + mi * 16 + lq * 4 + reg;
            #pragma unroll
            for (int ni = 0; ni < 4; ++ni)
                O_s[((size_t)(base + r)) * 64 + ni * 16 + lm] = O[mi][ni][reg];
        }
}

// ---- t2combine body ----
__device__ __forceinline__ void t2c_body(int idx, const float* __restrict__ O_s,
        const float* __restrict__ l_s, __bf16* __restrict__ t2th,
        __bf16* __restrict__ t2tl) {
    int bh = idx >> 14, r = (idx >> 6) & 255, d = idx & 63;
    float den = 0.f, num = 0.f;
    #pragma unroll
    for (int s = 0; s < 16; ++s) {
        int b2 = (bh * 16 + s) * 256 + r;
        den += l_s[b2];
        num += O_s[(size_t)b2 * 64 + d];
    }
    float v = num / den;
    __bf16 hh = (__bf16)v;
    size_t di = ((size_t)bh * 64 + d) * 256 + r;   // transposed: [bh][d][r]
    t2th[di] = hh;
    t2tl[di] = (__bf16)(v - (float)hh);
}

// ---- depthwise conv body ----
__device__ __forceinline__ void conv_body(int bxx, int bh,
        const __bf16* __restrict__ vt, const float* __restrict__ resk,
        __bf16* __restrict__ convb, float* kfs) {
    int h = bh & 7;
    int d = threadIdx.x & 63, tg = threadIdx.x >> 6;
    int t0 = bxx * 64 + tg * 16;
    if (threadIdx.x < 33) kfs[threadIdx.x] = resk[h * 33 + threadIdx.x];
    __syncthreads();
    const __bf16* row = vt + ((size_t)bh * 64 + d) * 8192;
    float win[48];
    #pragma unroll
    for (int c = 0; c < 6; ++c) {
        int tok0 = t0 - 16 + c * 8;
        if (tok0 >= 0 && tok0 + 7 < 8192) {
            bf16x8 v8 = *(const bf16x8*)&row[tok0];
            #pragma unroll
            for (int e = 0; e < 8; ++e) win[c * 8 + e] = (float)v8[e];
        } else {
            #pragma unroll
            for (int e = 0; e < 8; ++e) {
                int tok = tok0 + e;
                win[c * 8 + e] = (tok >= 0 && tok < 8192) ? (float)row[tok] : 0.f;
            }
        }
    }
    float o[16];
    #pragma unroll
    for (int i = 0; i < 16; ++i) o[i] = 0.f;
    #pragma unroll
    for (int j = 0; j < 33; ++j) {
        float kf = kfs[j];
        #pragma unroll
        for (int i = 0; i < 16; ++i) o[i] += kf * win[i + j];
    }
    __bf16* outr = convb + ((size_t)bh * 8192) * 64 + d;
    #pragma unroll
    for (int i = 0; i < 16; ++i)
        outr[(size_t)(t0 + i) * 64] = (__bf16)o[i];
}

// ================= kernels =================

// ---- F1: cvt(8192) + transpose(wqkv)(192) + transpose(wout)(64) ----
__global__ __launch_bounds__(256) void k_fuse_pre(const float* __restrict__ x,
        __bf16* __restrict__ xb, float* __restrict__ stats,
        const float* __restrict__ wqkv, __bf16* __restrict__ wqkvt,
        const float* __restrict__ wout, __bf16* __restrict__ woutt) {
    __shared__ __bf16 tile[64 * 72];
    int id = blockIdx.x;
    if (id < 8192) {
        if (id == 0 && threadIdx.x == 0) { stats[0] = 1.f; stats[1] = 0.f; }
        cvt_body(id, x, xb);
    } else if (id < 8384) {
        int lid = id - 8192;
        tf32_body(wqkv, wqkvt, 512, 1536, lid & 7, lid >> 3, tile);
    } else {
        int lid = id - 8384;
        tf32_body(wout, woutt, 512, 512, lid & 7, lid >> 3, tile);
    }
}

// ---- big GEMM: C = A(MxK,bf16) @ Bt(NxK,bf16)^T, 128x128 tile ----
template<int MODE>
__global__ __launch_bounds__(256) void k_gemm_big(const __bf16* __restrict__ A,
        const __bf16* __restrict__ Bt, int K,
        __bf16* __restrict__ qp, __bf16* __restrict__ kp, __bf16* __restrict__ vp,
        float* __restrict__ outp, const float* __restrict__ bias) {
    __shared__ __bf16 sA[128 * 64];
    __shared__ __bf16 sB[128 * 64];
    constexpr int NT  = (MODE == 0) ? 12 : 4;      // n-tiles
    constexpr int TOT = (MODE == 0) ? 3072 : 1024; // total blocks
    int flat = blockIdx.x;
    int t = (flat & 7) * (TOT / 8) + (flat >> 3);
    int m0 = (t / NT) * 128, n0 = (t % NT) * 128;
    int tid = threadIdx.x;
    int wave = tid >> 6, l = tid & 63, lm = l & 15, lq = l >> 4;
    int wm = wave & 1, wn = wave >> 1;
    int lr = l >> 3, lc8 = l & 7;
    int src_c = (lc8 ^ lr) * 8;          // inverse-swizzled source column
    f32x4 acc[4][4] = {};
    for (int k0 = 0; k0 < K; k0 += 64) {
        #pragma unroll
        for (int i = 0; i < 4; ++i) {
            int g = wave * 4 + i;        // 8-row group
            gload16(&A[(size_t)(m0 + g * 8 + lr) * K + k0 + src_c], &sA[g * 512]);
        }
        #pragma unroll
        for (int i = 0; i < 4; ++i) {
            int g = wave * 4 + i;
            gload16(&Bt[(size_t)(n0 + g * 8 + lr) * K + k0 + src_c], &sB[g * 512]);
        }
        __syncthreads();
        #pragma unroll
        for (int ko = 0; ko < 2; ++ko) {
            int ch = (ko << 2) | lq;     // chunk index 0..7
            bf16x8 af[4], bfr[4];
            #pragma unroll
            for (int mi = 0; mi < 4; ++mi) {
                int r = wm * 64 + mi * 16 + lm;
                af[mi] = *(bf16x8*)&sA[r * 64 + ((ch ^ (r & 7)) << 3)];
            }
            #pragma unroll
            for (int ni = 0; ni < 4; ++ni) {
                int r = wn * 64 + ni * 16 + lm;
                bfr[ni] = *(bf16x8*)&sB[r * 64 + ((ch ^ (r & 7)) << 3)];
            }
            #pragma unroll
            for (int mi = 0; mi < 4; ++mi)
                #pragma unroll
                for (int ni = 0; ni < 4; ++ni)
                    acc[mi][ni] = mfma_bf16(af[mi], bfr[ni], acc[mi][ni]);
        }
        __syncthreads();
    }
    #pragma unroll
    for (int mi = 0; mi < 4; ++mi)
    #pragma unroll
    for (int ni = 0; ni < 4; ++ni)
    #pragma unroll
    for (int reg = 0; reg < 4; ++reg) {
        int gr = m0 + wm * 64 + mi * 16 + lq * 4 + reg;
        int gc = n0 + wn * 64 + ni * 16 + lm;
        float v = acc[mi][ni][reg];
        if (MODE == 0) {
            int which = gc >> 9, rem = gc & 511;
            int h = rem >> 6, d = rem & 63;
            int b = gr >> 13, tok = gr & 8191;
            size_t dst = ((size_t)((b * 8 + h) * 8192 + tok)) * 64 + d;
            if (which == 0)      qp[dst] = (__bf16)(v * 0.125f);
            else if (which == 1) kp[dst] = (__bf16)v;
            else                 vp[dst] = (__bf16)v;
        } else {
            outp[(size_t)gr * 512 + gc] = v + bias[gc];
        }
    }
}

// ---- F2: v-transpose(4096) + landmarks(4096) ----
__global__ __launch_bounds__(256) void k_fuse_tl(const __bf16* __restrict__ vsrc,
        __bf16* __restrict__ vt, const __bf16* __restrict__ q,
        const __bf16* __restrict__ k, __bf16* __restrict__ ql,
        __bf16* __restrict__ kl) {
    __shared__ __bf16 tile[64 * 72];
    int id = blockIdx.x;
    if (id < 4096) {
        tbf_body(vsrc, vt, id & 127, id >> 7, tile);
    } else {
        landmarks_body((id - 4096) * 256 + threadIdx.x, q, k, ql, kl);
    }
}

// ---- attn2 = softmax(q_l @ k_l^T), hi/lo bf16 planes ----
__global__ __launch_bounds__(256) void k_attn2(const __bf16* __restrict__ ql,
        const __bf16* __restrict__ kl, __bf16* __restrict__ ph, __bf16* __restrict__ pl) {
    int tid = threadIdx.x;
    int wave = tid >> 6, l = tid & 63, lm = l & 15, lq = l >> 4;
    int bh = blockIdx.y;
    int r0 = blockIdx.x * 64 + wave * 16;
    const __bf16* qb = ql + (size_t)bh * 16384;
    const __bf16* kb = kl + (size_t)bh * 16384;
    bf16x8 af[2];
    #pragma unroll
    for (int ko = 0; ko < 2; ++ko)
        af[ko] = *(const bf16x8*)&qb[(size_t)(r0 + lm) * 64 + ko * 32 + lq * 8];
    f32x4 S[16] = {};
    #pragma unroll
    for (int ci = 0; ci < 16; ++ci)
        #pragma unroll
        for (int ko = 0; ko < 2; ++ko) {
            bf16x8 bfr = *(const bf16x8*)&kb[(size_t)(ci * 16 + lm) * 64 + ko * 32 + lq * 8];
            S[ci] = mfma_bf16(af[ko], bfr, S[ci]);
        }
    __bf16* oh = ph + (size_t)bh * 65536;
    __bf16* ol = pl + (size_t)bh * 65536;
    #pragma unroll
    for (int reg = 0; reg < 4; ++reg) {
        float sum = 0.f;
        #pragma unroll
        for (int ci = 0; ci < 16; ++ci) {
            float e = __expf(S[ci][reg]); S[ci][reg] = e; sum += e;
        }
        #pragma unroll
        for (int msk = 1; msk < 16; msk <<= 1) sum += __shfl_xor(sum, msk);
        float inv = 1.f / sum;
        int row = r0 + lq * 4 + reg;
        #pragma unroll
        for (int ci = 0; ci < 16; ++ci) {
            float v = S[ci][reg] * inv;
            __bf16 hh = (__bf16)v;
            oh[(size_t)row * 256 + ci * 16 + lm] = hh;
            ol[(size_t)row * 256 + ci * 16 + lm] = (__bf16)(v - (float)hh);
        }
    }
}

// ---- max col-sum of attn2 (row-sums are exactly 1) ----
__global__ __launch_bounds__(256) void k_stats(const __bf16* __restrict__ ph,
        const __bf16* __restrict__ pl, float* stats) {
    __shared__ float red[256];
    int tid = threadIdx.x;
    const __bf16* a = ph + (size_t)blockIdx.x * 65536;
    const __bf16* b = pl + (size_t)blockIdx.x * 65536;
    float cs = 0.f;
    for (int r = 0; r < 256; ++r)
        cs += (float)a[r * 256 + tid] + (float)b[r * 256 + tid];
    red[tid] = cs; __syncthreads();
    for (int off = 128; off > 0; off >>= 1) {
        if (tid < off) red[tid] = fmaxf(red[tid], red[tid + off]);
        __syncthreads();
    }
    if (tid == 0) atomicMax((int*)&stats[1], __float_as_int(red[0]));
}

// ---- F3: attn3(512) + z0t(512) + A0(1024)  [conv NOT here: convb aliases O_s] ----
__global__ __launch_bounds__(256) void k_fuse_mid(
        const __bf16* __restrict__ ql, const __bf16* __restrict__ kbf,
        const __bf16* __restrict__ vt, float* __restrict__ O_s,
        float* __restrict__ l_s, const __bf16* __restrict__ a2h,
        const __bf16* __restrict__ a2l, const float* __restrict__ stats,
        __bf16* __restrict__ zAh, __bf16* __restrict__ zAl,
        __bf16* __restrict__ Amh, __bf16* __restrict__ Aml) {
    __shared__ __attribute__((aligned(16))) char smem[24576];
    int id = blockIdx.x;
    if (id < 512) {
        attn3_body(id & 15, id >> 4, ql, kbf, vt, O_s, l_s);
    } else if (id < 1024) {
        __bf16* th = (__bf16*)smem;
        __bf16* tl = (__bf16*)(smem + 9216);
        z0t_body(id - 512, a2h, a2l, stats, zAh, zAl, th, tl);
    } else {
        __bf16* sAh = (__bf16*)smem;
        __bf16* sAl = (__bf16*)(smem + 4096);
        __bf16* sBh = (__bf16*)(smem + 8192);
        __bf16* sBl = (__bf16*)(smem + 16384);
        float sc = 1.f / (stats[0] * stats[1]);
        pgemm_stage(id - 1024, 1024, a2h, a2l, a2h, a2l, nullptr, nullptr,
                    Amh, Aml, sc, 0.f, 0.f, 0, 65536, sAh, sAl, sBh, sBl);
    }
}

// ---- F4: W2_0(1024) + t2combine(2048)  [t2combine drains O_s here] ----
__global__ __launch_bounds__(256) void k_fuse_w2t2(
        const __bf16* __restrict__ Amh, const __bf16* __restrict__ Aml,
        __bf16* __restrict__ W2h, __bf16* __restrict__ W2l,
        const float* __restrict__ O_s, const float* __restrict__ l_s,
        __bf16* __restrict__ t2th, __bf16* __restrict__ t2tl) {
    __shared__ __bf16 sAh[32 * 64], sAl[32 * 64], sBh[64 * 64], sBl[64 * 64];
    int id = blockIdx.x;
    if (id < 1024) {
        pgemm_stage(id, 1024, Amh, Aml, Amh, Aml, Amh, Aml, W2h, W2l,
                    1.f, -7.f, 15.f, 0, 65536, sAh, sAl, sBh, sBl);
    } else {
        t2c_body((id - 1024) * 256 + threadIdx.x, O_s, l_s, t2th, t2tl);
    }
}

// ---- F5: W3_0(1024) + conv(4096)  [conv safe: O_s drained by F4] ----
__global__ __launch_bounds__(256) void k_fuse_w3conv(
        const __bf16* __restrict__ Amh, const __bf16* __restrict__ Aml,
        const __bf16* __restrict__ W2h, const __bf16* __restrict__ W2l,
        __bf16* __restrict__ W3h, __bf16* __restrict__ W3l,
        const __bf16* __restrict__ vt, const float* __restrict__ resk,
        __bf16* __restrict__ convb) {
    __shared__ __bf16 sAh[32 * 64], sAl[32 * 64], sBh[64 * 64], sBl[64 * 64];
    __shared__ float kfs[33];
    int id = blockIdx.x;
    if (id < 1024) {
        pgemm_stage(id, 1024, Amh, Aml, W2h, W2l, nullptr, nullptr, W3h, W3l,
                    -1.f, 0.f, 13.f, 0, 65536, sAh, sAl, sBh, sBl);
    } else {
        int lid = id - 1024;
        conv_body(lid & 127, lid >> 7, vt, resk, convb, kfs);
    }
}

// ---- standalone chain stage ----
__global__ __launch_bounds__(256) void k_pgemm(const __bf16* __restrict__ Ah,
        const __bf16* __restrict__ Al, const __bf16* __restrict__ Bth,
        const __bf16* __restrict__ Btl, const __bf16* __restrict__ Ch,
        const __bf16* __restrict__ Cl, __bf16* __restrict__ OutH,
        __bf16* __restrict__ OutL, float alpha, const float* __restrict__ sPtr,
        float beta, float delta, int outMode, long bStride) {
    __shared__ __bf16 sAh[32 * 64], sAl[32 * 64], sBh[64 * 64], sBl[64 * 64];
    float aEff = alpha;
    if (sPtr) aEff *= 1.f / (sPtr[0] * sPtr[1]);
    pgemm_stage(blockIdx.x, gridDim.x, Ah, Al, Bth, Btl, Ch, Cl, OutH, OutL,
                aEff, beta, delta, outMode, bStride, sAh, sAl, sBh, sBl);
}

// ---- dual update: z' = 0.25 z@W3 (zz<32), A' = 0.25 A@W3 (zz>=32) ----
__global__ __launch_bounds__(256) void k_pgemm_dual(const __bf16* __restrict__ Zh,
        const __bf16* __restrict__ Zl, const __bf16* __restrict__ A2h,
        const __bf16* __restrict__ A2l, const __bf16* __restrict__ Bth,
        const __bf16* __restrict__ Btl, __bf16* __restrict__ OzH,
        __bf16* __restrict__ OzL, __bf16* __restrict__ OaH, __bf16* __restrict__ OaL) {
    __shared__ __bf16 sAh[32 * 64], sAl[32 * 64], sBh[64 * 64], sBl[64 * 64];
    int tid = threadIdx.x;
    int wave = tid >> 6, l = tid & 63, lm = l & 15, lq = l >> 4;
    int wm = wave & 1, wn = wave >> 1;
    int total = gridDim.x;
    int flat = blockIdx.x;
    int t = (flat & 7) * (total >> 3) + (flat >> 3);
    int zz = t >> 5, rem = t & 31;
    int m0 = (rem >> 2) * 32, n0 = (rem & 3) * 64;
    int bh = zz & 31;
    const __bf16* Lh = (zz >= 32 ? A2h : Zh) + (size_t)bh * 65536;
    const __bf16* Ll = (zz >= 32 ? A2l : Zl) + (size_t)bh * 65536;
    __bf16* Oh = (zz >= 32 ? OaH : OzH) + (size_t)bh * 65536;
    __bf16* Ol = (zz >= 32 ? OaL : OzL) + (size_t)bh * 65536;
    f32x4 acc[2] = {};
    pgemm_core(Lh, Ll, Bth + (size_t)bh * 65536, Btl + (size_t)bh * 65536,
               m0, n0, sAh, sAl, sBh, sBl, acc);
    #pragma unroll
    for (int ni = 0; ni < 2; ++ni)
    #pragma unroll
    for (int reg = 0; reg < 4; ++reg) {
        int gr = m0 + wm * 16 + lq * 4 + reg;
        int gc = n0 + wn * 32 + ni * 16 + lm;
        float v = 0.25f * acc[ni][reg];
        __bf16 hh = (__bf16)v;
        Oh[(size_t)gr * 256 + gc] = hh;
        Ol[(size_t)gr * 256 + gc] = (__bf16)(v - (float)hh);
    }
}

// ---- attn1 fused: softmax(q k_l^T) @ zt2 + convb (64 rows/wave, zero LDS) ----
__global__ __launch_bounds__(256) void k_attn1(const __bf16* __restrict__ q,
        const __bf16* __restrict__ kl, const __bf16* __restrict__ zt2p,
        const __bf16* __restrict__ convb, __bf16* __restrict__ outp) {
    int tid = threadIdx.x;
    int wave = tid >> 6, l = tid & 63, lm = l & 15, lq = l >> 4;
    int bh = blockIdx.y;
    int t0 = blockIdx.x * 256;
    int b = bh >> 3, h = bh & 7;
    const __bf16* qb = q + (size_t)bh * 8192 * 64;
    const __bf16* kb = kl + (size_t)bh * 16384;
    const __bf16* zb = zt2p + (size_t)bh * 16384;
    int rowb = t0 + wave * 64;
    bf16x8 qa[4][2];
    #pragma unroll
    for (int mi = 0; mi < 4; ++mi)
        #pragma unroll
        for (int ko = 0; ko < 2; ++ko)
            qa[mi][ko] = *(const bf16x8*)&qb[(size_t)(rowb + mi * 16 + lm) * 64 + ko * 32 + lq * 8];
    f32x4 O[4][4] = {};
    float rs[4] = {};
    #pragma unroll
    for (int c2 = 0; c2 < 8; ++c2) {       // 2 landmark-col blocks per chunk
        bf16x8 kf[2][2];
        #pragma unroll
        for (int ci = 0; ci < 2; ++ci)
            #pragma unroll
            for (int ko = 0; ko < 2; ++ko)
                kf[ci][ko] = *(const bf16x8*)&kb[(size_t)((c2 * 2 + ci) * 16 + lm) * 64 + ko * 32 + lq * 8];
        f32x4 St[4][2] = {};
        #pragma unroll
        for (int ci = 0; ci < 2; ++ci)
            #pragma unroll
            for (int ko = 0; ko < 2; ++ko)
                #pragma unroll
                for (int mi = 0; mi < 4; ++mi)
                    St[mi][ci] = mfma_bf16(kf[ci][ko], qa[mi][ko], St[mi][ci]);
        bf16x4 pk[4][2];
        #pragma unroll
        for (int mi = 0; mi < 4; ++mi)
            #pragma unroll
            for (int ci = 0; ci < 2; ++ci)
                #pragma unroll
                for (int reg = 0; reg < 4; ++reg) {
                    float e = __expf(St[mi][ci][reg]);
                    rs[mi] += e;
                    pk[mi][ci][reg] = (__bf16)e;
                }
        bf16x8 zfr[4];
        #pragma unroll
        for (int ni = 0; ni < 4; ++ni)
            zfr[ni] = *(const bf16x8*)&zb[(size_t)(ni * 16 + lm) * 256 + c2 * 32 + lq * 8];
        #pragma unroll
        for (int mi = 0; mi < 4; ++mi) {
            bf16x8 af;
            #pragma unroll
            for (int r = 0; r < 4; ++r) {
                af[r]     = pk[mi][0][r];
                af[4 + r] = pk[mi][1][r];
            }
            #pragma unroll
            for (int ni = 0; ni < 4; ++ni)
                O[mi][ni] = mfma_bf16(af, zfr[ni], O[mi][ni]);
        }
    }
    #pragma unroll
    for (int mi = 0; mi < 4; ++mi) {
        float v = rs[mi];
        v += __shfl_xor(v, 16);
        v += __shfl_xor(v, 32);            // rowsum(rowb+mi*16+lm) on all lq-copies
        float invr[4];
        #pragma unroll
        for (int reg = 0; reg < 4; ++reg)
            invr[reg] = 1.f / __shfl(v, lq * 4 + reg);
        #pragma unroll
        for (int ni = 0; ni < 4; ++ni)
            #pragma unroll
            for (int reg = 0; reg < 4; ++reg) {
                int tok = rowb + mi * 16 + lq * 4 + reg;
                int d = ni * 16 + lm;
                float conv = (float)convb[((size_t)bh * 8192 + tok) * 64 + d];
                float val = O[mi][ni][reg] * invr[reg] + conv;
                outp[((size_t)(b * 8192 + tok)) * 512 + h * 64 + d] = (__bf16)val;
            }
    }
}

// ---------------- launcher ----------------
extern "C" void kernel_launch(void* const* d_in, const int* in_sizes, int n_in,
                              void* d_out, int out_size, void* d_ws, size_t ws_size,
                              hipStream_t stream) {
    const float* x    = (const float*)d_in[0];
    const float* wqkv = (const float*)d_in[1];
    const float* wout = (const float*)d_in[2];
    const float* bout = (const float*)d_in[3];
    const float* resk = (const float*)d_in[4];
    char* ws = (char*)d_ws;
    size_t off = 0;
    auto alloc = [&](size_t bytes) {
        char* p = ws + off;
        off += (bytes + 255) & ~(size_t)255;
        return p;
    };
    const size_t PL = 2097152;                   // elems per 4MB bf16 plane (32x256x256)
    __bf16* q_bf   = (__bf16*)alloc(33554432);   // (bh,n,d)
    __bf16* k_bf   = (__bf16*)alloc(33554432);   // (bh,n,d)
    __bf16* vt     = (__bf16*)alloc(33554432);   // (bh,d,n)
    __bf16* outpre = (__bf16*)alloc(33554432);   // v_tmp early, attn1 out later
    __bf16* q_l    = (__bf16*)alloc(1048576);
    __bf16* k_l    = (__bf16*)alloc(1048576);
    __bf16* a2h    = (__bf16*)alloc(8388608);    // attn2 hi/lo planes; An slot later
    __bf16* zAh    = (__bf16*)alloc(8388608);
    __bf16* zBh    = (__bf16*)alloc(8388608);
    __bf16* Amh    = (__bf16*)alloc(8388608);
    __bf16* W2h    = (__bf16*)alloc(8388608);
    __bf16* W3h    = (__bf16*)alloc(8388608);
    float*  O_s    = (float*)alloc(33554432);    // xb early, attn3 out, convb late
    float*  l_s    = (float*)alloc(524288);
    __bf16* t2th   = (__bf16*)alloc(2097152);    // t2^T hi/lo planes (1MB each)
    __bf16* zt2t   = (__bf16*)alloc(1048576);
    __bf16* wqkvt  = (__bf16*)alloc(1572864);
    __bf16* woutt  = (__bf16*)alloc(524288);
    float*  stats  = (float*)alloc(256);
    __bf16* convb  = (__bf16*)O_s;               // alias (32 MB <= 33.5 MB)
    __bf16* xb     = (__bf16*)O_s;               // alias: x bf16, dead before attn3
    __bf16* a2l = a2h + PL;
    __bf16* zAl = zAh + PL;
    __bf16* zBl = zBh + PL;
    __bf16* Aml = Amh + PL;
    __bf16* W2l = W2h + PL;
    __bf16* W3l = W3h + PL;
    __bf16* t2tl = t2th + 524288;

    // F1: cvt + weight transposes (+ stats init)
    k_fuse_pre<<<8448, 256, 0, stream>>>(x, xb, stats, wqkv, wqkvt, wout, woutt);
    k_gemm_big<0><<<3072, 256, 0, stream>>>(xb, wqkvt, 512,
            q_bf, k_bf, outpre, nullptr, nullptr);
    // F2: v-transpose + landmarks
    k_fuse_tl<<<8192, 256, 0, stream>>>(outpre, vt, q_bf, k_bf, q_l, k_l);
    k_attn2<<<dim3(4, 32), 256, 0, stream>>>(q_l, k_l, a2h, a2l);
    k_stats<<<32, 256, 0, stream>>>(a2h, a2l, stats);
    // F3: attn3 + z0t + A0 (conv excluded: convb aliases O_s)
    k_fuse_mid<<<2048, 256, 0, stream>>>(q_l, k_bf, vt, O_s, l_s,
            a2h, a2l, stats, zAh, zAl, Amh, Aml);
    // F4: W2_0 + t2combine (consumes O_s)
    k_fuse_w2t2<<<3072, 256, 0, stream>>>(Amh, Aml, W2h, W2l, O_s, l_s, t2th, t2tl);
    // F5: W3_0 + conv (O_s now dead -> convb reuse safe)
    k_fuse_w3conv<<<5120, 256, 0, stream>>>(Amh, Aml, W2h, W2l, W3h, W3l,
            vt, resk, convb);

    __bf16 *zch = zAh, *zcl = zAl, *znh = zBh, *znl = zBl;
    __bf16 *Ach = Amh, *Acl = Aml, *Anh = a2h, *Anl = a2l;   // attn2 planes dead after A0
    for (int it = 0; it < 6; ++it) {
        if (it > 0) {
            k_pgemm<<<1024, 256, 0, stream>>>(Ach, Acl, Ach, Acl,
                    Ach, Acl, W2h, W2l, 1.f, nullptr, -7.f, 15.f, 0, 65536); // W2 = 15I - 7A + A@A
            k_pgemm<<<1024, 256, 0, stream>>>(Ach, Acl, W2h, W2l,
                    nullptr, nullptr, W3h, W3l, -1.f, nullptr, 0.f, 13.f, 0, 65536); // W3 = 13I - A@W2
        }
        if (it < 5) {
            k_pgemm_dual<<<2048, 256, 0, stream>>>(zch, zcl, Ach, Acl,
                    W3h, W3l, znh, znl, Anh, Anl);
            __bf16* t;
            t = Ach; Ach = Anh; Anh = t;
            t = Acl; Acl = Anl; Anl = t;
        } else {
            k_pgemm_dual<<<1024, 256, 0, stream>>>(zch, zcl, zch, zcl,
                    W3h, W3l, znh, znl, znh, znl);
        }
        __bf16* t;
        t = zch; zch = znh; znh = t;
        t = zcl; zcl = znl; znl = t;
    }
    // zt2t[bh][d][slot] = (z_final @ t2)^T, bf16, slot-permuted for attn1's PV
    k_pgemm<<<256, 256, 0, stream>>>(zch, zcl, t2th, t2tl,
            nullptr, nullptr, zt2t, nullptr, 1.f, nullptr, 0.f, 0.f, 1, 16384);
    k_attn1<<<dim3(32, 32), 256, 0, stream>>>(q_bf, k_l, zt2t, convb, outpre);
    k_gemm_big<1><<<1024, 256, 0, stream>>>(outpre, woutt, 512,
            nullptr, nullptr, nullptr, (float*)d_out, bout);
}

// Round 13
// 615.923 us; speedup vs baseline: 1.0195x; 1.0195x over previous
//
#include <hip/hip_runtime.h>
#include <stdint.h>
#include <stddef.h>

// RRT/Nystrom attention, MI355X gfx950.
// Inputs/outputs FLOAT32. Heavy GEMMs: bf16 MFMA + fp32 accumulate,
// staged via global_load_lds(16B) with XOR chunk-swizzle (rule #21:
// linear LDS dest + inverse-swizzled global source + swizzled read).
// k_gemm_big blocks are XCD-chunked and A-panel-major (FETCH 117->31MB).
// Moore-Penrose chain: hi/lo bf16 planes split ONCE by each producer
// (fp32-grade via 3-plane MFMA). All chain matrices are symmetric
// (polynomials of A0 = s*attn2@attn2^T) -> B^T-rows = rows of same plane.
// Chain: DISCRETE launches, 32x64 tiles (measured optimal; in-kernel
// cross-WG sync costs 42-140us/barrier vs ~7us kernel boundary).
// LAUNCH-COUNT REDUCTION: independent DAG siblings block-partition-fused.
// ALIAS DISCIPLINE: convb ALIASES O_s -> conv runs strictly AFTER
// t2combine reads O_s. Fusion schedule:
//   F1 = cvt + W-transposes; F2 = v-transpose + landmarks;
//   F3 = attn3 + z0t + A0;  F4 = W2_0 + t2combine;  F5 = W3_0 + conv.
// attn3 prefetches next iteration's K fragments after the QK MFMAs.
// THIS ROUND: z0t transpose uses stride-65 scalar-LDS (write spacing 8
// elems, read spacing 520 elems -> 8 distinct banks each; was stride-72
// with (576/2)%32==0 -> 8-way same-bank conflict, 917K/dispatch).
// Global accesses stay bf16x8-vectorized. Zero numerics change.
// Softmaxes WITHOUT max-subtraction: scores O(1) by construction.
// attn1/attn3: swapped-QK^T keeps P-rows lane-local; PV A-frag built
// in-register via k-slot permutation; zt2t stored pre-permuted.

typedef __bf16 bf16x8 __attribute__((ext_vector_type(8)));
typedef __bf16 bf16x4 __attribute__((ext_vector_type(4)));
typedef float f32x4 __attribute__((ext_vector_type(4)));

__device__ __forceinline__ f32x4 mfma_bf16(bf16x8 a, bf16x8 b, f32x4 c) {
    return __builtin_amdgcn_mfma_f32_16x16x32_bf16(a, b, c, 0, 0, 0);
}

__device__ __forceinline__ void gload16(const __bf16* g, __bf16* l) {
    __builtin_amdgcn_global_load_lds(
        (const __attribute__((address_space(1))) void*)g,
        (__attribute__((address_space(3))) void*)l, 16, 0, 0);
}

// ================= device bodies =================

// ---- x f32 -> bf16 ----
__device__ __forceinline__ void cvt_body(int bid, const float* __restrict__ in,
        __bf16* __restrict__ out) {
    size_t base = ((size_t)bid * 256 + threadIdx.x) * 8;
    float4 a = *(const float4*)&in[base];
    float4 b = *(const float4*)&in[base + 4];
    bf16x8 o;
    o[0] = (__bf16)a.x; o[1] = (__bf16)a.y; o[2] = (__bf16)a.z; o[3] = (__bf16)a.w;
    o[4] = (__bf16)b.x; o[5] = (__bf16)b.y; o[6] = (__bf16)b.z; o[7] = (__bf16)b.w;
    *(bf16x8*)&out[base] = o;
}

// ---- f32 -> bf16 transposed copy (weights), 64x64 tile ----
__device__ __forceinline__ void tf32_body(const float* __restrict__ in,
        __bf16* __restrict__ out, int R, int C, int bx, int by, __bf16* tile) {
    int r0 = bx * 64, c0 = by * 64;
    int tid = threadIdx.x;
    #pragma unroll
    for (int i = 0; i < 16; ++i) {
        int slot = i * 256 + tid;
        int rr = slot >> 6, cc = slot & 63;
        tile[rr * 72 + cc] = (__bf16)in[(size_t)(r0 + rr) * C + c0 + cc];
    }
    __syncthreads();
    #pragma unroll
    for (int i = 0; i < 2; ++i) {
        int slot = i * 256 + tid;
        int cc = slot >> 3, s = slot & 7;
        bf16x8 t;
        #pragma unroll
        for (int j = 0; j < 8; ++j) t[j] = tile[(s * 8 + j) * 72 + cc];
        *(bf16x8*)&out[(size_t)(c0 + cc) * R + r0 + s * 8] = t;
    }
}

// ---- bf16 transpose 64x64 (v -> vt), batch bz ----
__device__ __forceinline__ void tbf_body(const __bf16* __restrict__ in0,
        __bf16* __restrict__ out0, int bx, int bz, __bf16* tile) {
    const __bf16* in = in0 + (size_t)bz * 524288;
    __bf16* out = out0 + (size_t)bz * 524288;
    int r0 = bx * 64, c0 = 0;               // R=8192, C=64
    int tid = threadIdx.x;
    #pragma unroll
    for (int i = 0; i < 2; ++i) {
        int slot = i * 256 + tid;
        int rr = slot >> 3, s = slot & 7;
        *(bf16x8*)&tile[rr * 72 + s * 8] =
            *(const bf16x8*)&in[(size_t)(r0 + rr) * 64 + c0 + s * 8];
    }
    __syncthreads();
    #pragma unroll
    for (int i = 0; i < 2; ++i) {
        int slot = i * 256 + tid;
        int cc = slot >> 3, s = slot & 7;
        bf16x8 t;
        #pragma unroll
        for (int j = 0; j < 8; ++j) t[j] = tile[(s * 8 + j) * 72 + cc];
        *(bf16x8*)&out[(size_t)(c0 + cc) * 8192 + r0 + s * 8] = t;
    }
}

// ---- landmark means ----
__device__ __forceinline__ void landmarks_body(int idx, const __bf16* __restrict__ q,
        const __bf16* __restrict__ k, __bf16* __restrict__ ql, __bf16* __restrict__ kl) {
    int sel = idx >> 19;
    int rem = idx & 524287;
    int bh = rem >> 14;
    int m  = (rem >> 6) & 255;
    int d  = rem & 63;
    const __bf16* src = sel ? k : q;
    __bf16* dst = sel ? kl : ql;
    const __bf16* p = src + ((size_t)(bh * 8192 + m * 32)) * 64 + d;
    float s = 0.f;
    #pragma unroll
    for (int j = 0; j < 32; ++j) s += (float)p[j * 64];
    dst[(size_t)bh * 16384 + m * 64 + d] = (__bf16)(s * (1.f / 32.f));
}

// ---- z0 tile: z0 = attn2^T / colsum_max, hi/lo planes, 64x64 LDS transpose ----
// stride-65 scalar LDS both sides: write spacing 8 elems, read spacing 520
// elems -> 8 distinct banks each (no conflicts). Global side stays bf16x8.
__device__ __forceinline__ void z0t_body(int tileid, const __bf16* __restrict__ ph,
        const __bf16* __restrict__ pl, const float* __restrict__ stats,
        __bf16* __restrict__ zh, __bf16* __restrict__ zl,
        __bf16* th, __bf16* tl) {
    int bh = tileid >> 4;
    int r0 = ((tileid >> 2) & 3) * 64, c0 = (tileid & 3) * 64;
    const __bf16* ah = ph + (size_t)bh * 65536;
    const __bf16* al = pl + (size_t)bh * 65536;
    int tid = threadIdx.x;
    #pragma unroll
    for (int i = 0; i < 2; ++i) {
        int slot = i * 256 + tid;
        int rr = slot >> 3, s = slot & 7;   // a2 row c0+rr, cols r0+s*8..
        bf16x8 vh = *(const bf16x8*)&ah[(size_t)(c0 + rr) * 256 + r0 + s * 8];
        bf16x8 vl = *(const bf16x8*)&al[(size_t)(c0 + rr) * 256 + r0 + s * 8];
        #pragma unroll
        for (int j = 0; j < 8; ++j) {
            th[rr * 65 + s * 8 + j] = vh[j];
            tl[rr * 65 + s * 8 + j] = vl[j];
        }
    }
    __syncthreads();
    float inv = 1.f / (stats[0] * stats[1]);
    #pragma unroll
    for (int i = 0; i < 2; ++i) {
        int slot = i * 256 + tid;
        int cc = slot >> 3, s = slot & 7;   // out row r0+cc, cols c0+s*8..
        bf16x8 oh2, ol2;
        #pragma unroll
        for (int j = 0; j < 8; ++j) {
            float v = ((float)th[(s * 8 + j) * 65 + cc] +
                       (float)tl[(s * 8 + j) * 65 + cc]) * inv;
            __bf16 hh = (__bf16)v;
            oh2[j] = hh;
            ol2[j] = (__bf16)(v - (float)hh);
        }
        size_t di = ((size_t)bh << 16) + (size_t)(r0 + cc) * 256 + c0 + s * 8;
        *(bf16x8*)&zh[di] = oh2;
        *(bf16x8*)&zl[di] = ol2;
    }
}

// ---- plane GEMM core: 32x64 tile, K=256, LDS-staged, XOR swizzle ----
__device__ __forceinline__ void pgemm_core(const __bf16* __restrict__ Ah,
        const __bf16* __restrict__ Al, const __bf16* __restrict__ Bth,
        const __bf16* __restrict__ Btl, int m0, int n0,
        __bf16* sAh, __bf16* sAl, __bf16* sBh, __bf16* sBl, f32x4 acc[2]) {
    int tid = threadIdx.x;
    int wave = tid >> 6, l = tid & 63, lm = l & 15, lq = l >> 4;
    int wm = wave & 1, wn = wave >> 1;
    int lr = l >> 3, lc8 = l & 7;
    int src_c = (lc8 ^ lr) * 8;
    for (int k0 = 0; k0 < 256; k0 += 64) {
        {
            size_t ra = (size_t)(m0 + wave * 8 + lr) * 256 + k0 + src_c;
            gload16(&Ah[ra], &sAh[wave * 512]);
            gload16(&Al[ra], &sAl[wave * 512]);
        }
        #pragma unroll
        for (int i = 0; i < 2; ++i) {
            int g = wave * 2 + i;
            size_t rb = (size_t)(n0 + g * 8 + lr) * 256 + k0 + src_c;
            gload16(&Bth[rb], &sBh[g * 512]);
            gload16(&Btl[rb], &sBl[g * 512]);
        }
        __syncthreads();
        #pragma unroll
        for (int ko = 0; ko < 2; ++ko) {
            int ch = (ko << 2) | lq;
            int rA = wm * 16 + lm;
            int oA = rA * 64 + ((ch ^ (rA & 7)) << 3);
            bf16x8 a_h = *(bf16x8*)&sAh[oA];
            bf16x8 a_l = *(bf16x8*)&sAl[oA];
            bf16x8 b_h[2], b_l[2];
            #pragma unroll
            for (int ni = 0; ni < 2; ++ni) {
                int r = wn * 32 + ni * 16 + lm;
                int o = r * 64 + ((ch ^ (r & 7)) << 3);
                b_h[ni] = *(bf16x8*)&sBh[o];
                b_l[ni] = *(bf16x8*)&sBl[o];
            }
            #pragma unroll
            for (int ni = 0; ni < 2; ++ni) {
                acc[ni] = mfma_bf16(a_h, b_h[ni], acc[ni]);
                acc[ni] = mfma_bf16(a_h, b_l[ni], acc[ni]);
                acc[ni] = mfma_bf16(a_l, b_h[ni], acc[ni]);
            }
        }
        __syncthreads();
    }
}

// ---- one chain stage (32x64 tile); flat/total drive XCD-chunked remap ----
__device__ __forceinline__ void pgemm_stage(int flat, int total,
        const __bf16* __restrict__ Ah, const __bf16* __restrict__ Al,
        const __bf16* __restrict__ Bth, const __bf16* __restrict__ Btl,
        const __bf16* __restrict__ Ch, const __bf16* __restrict__ Cl,
        __bf16* __restrict__ OutH, __bf16* __restrict__ OutL,
        float aEff, float beta, float delta, int outMode, long bStride,
        __bf16* sAh, __bf16* sAl, __bf16* sBh, __bf16* sBl) {
    int tid = threadIdx.x;
    int wave = tid >> 6, l = tid & 63, lm = l & 15, lq = l >> 4;
    int wm = wave & 1, wn = wave >> 1;
    int t = (flat & 7) * (total >> 3) + (flat >> 3);
    int ntb = total >> 8;              // n-tiles per bh (4 or 1)
    int tpb = ntb << 3;                // tiles per bh
    int bh = t / tpb, rem = t - bh * tpb;
    int m0 = (rem / ntb) * 32, n0 = (rem % ntb) * 64;
    f32x4 acc[2] = {};
    pgemm_core(Ah + (size_t)bh * 65536, Al + (size_t)bh * 65536,
               Bth + (size_t)bh * bStride, Btl + (size_t)bh * bStride,
               m0, n0, sAh, sAl, sBh, sBl, acc);
    #pragma unroll
    for (int ni = 0; ni < 2; ++ni)
    #pragma unroll
    for (int reg = 0; reg < 4; ++reg) {
        int gr = m0 + wm * 16 + lq * 4 + reg;
        int gc = n0 + wn * 32 + ni * 16 + lm;
        float v = aEff * acc[ni][reg];
        if (beta != 0.f) {
            size_t ci = (size_t)bh * 65536 + (size_t)gr * 256 + gc;
            v += beta * ((float)Ch[ci] + (float)Cl[ci]);
        }
        if (gr == gc) v += delta;
        if (outMode == 0) {
            size_t di = (size_t)bh * 65536 + (size_t)gr * 256 + gc;
            __bf16 hh = (__bf16)v;
            OutH[di] = hh;
            OutL[di] = (__bf16)(v - (float)hh);
        } else {
            int ci2 = gr >> 4, lqm = (gr >> 2) & 3, r = gr & 3;
            int slot = ((ci2 >> 1) << 5) + (lqm << 3) + ((ci2 & 1) << 2) + r;
            OutH[(size_t)bh * 16384 + (size_t)gc * 256 + slot] = (__bf16)v;
        }
    }
}

// ---- attn3 flash body (swapped QK^T, P in-register, no LDS) ----
// K fragments for iteration it+1 are prefetched right after iteration it's
// QK MFMAs: the exp+PV phase hides the load latency.
__device__ __forceinline__ void attn3_body(int s, int bh,
        const __bf16* __restrict__ ql, const __bf16* __restrict__ kk,
        const __bf16* __restrict__ vt, float* __restrict__ O_s,
        float* __restrict__ l_s) {
    int tid = threadIdx.x;
    int wave = tid >> 6, l = tid & 63, lm = l & 15, lq = l >> 4;
    const __bf16* qb = ql + (size_t)bh * 16384;
    bf16x8 qa[4][2];
    #pragma unroll
    for (int mi = 0; mi < 4; ++mi)
        #pragma unroll
        for (int ko = 0; ko < 2; ++ko)
            qa[mi][ko] = *(const bf16x8*)&qb[(size_t)(wave * 64 + mi * 16 + lm) * 64 + ko * 32 + lq * 8];
    f32x4 O[4][4] = {};
    float lsum[4] = {};
    // preload K fragments for it=0
    bf16x8 kf[4][2];
    #pragma unroll
    for (int ci = 0; ci < 4; ++ci)
        #pragma unroll
        for (int ko = 0; ko < 2; ++ko)
            kf[ci][ko] = *(const bf16x8*)&kk[((size_t)bh * 8192 + s * 512 + ci * 16 + lm) * 64 + ko * 32 + lq * 8];
    for (int it = 0; it < 8; ++it) {
        int c0 = s * 512 + it * 64;
        f32x4 St[4][4] = {};
        #pragma unroll
        for (int ci = 0; ci < 4; ++ci)
            #pragma unroll
            for (int ko = 0; ko < 2; ++ko)
                #pragma unroll
                for (int mi = 0; mi < 4; ++mi)
                    St[mi][ci] = mfma_bf16(kf[ci][ko], qa[mi][ko], St[mi][ci]);
        // prefetch next iteration's K fragments (WAR after MFMAs above)
        if (it < 7) {
            int c1 = c0 + 64;
            #pragma unroll
            for (int ci = 0; ci < 4; ++ci)
                #pragma unroll
                for (int ko = 0; ko < 2; ++ko)
                    kf[ci][ko] = *(const bf16x8*)&kk[((size_t)bh * 8192 + c1 + ci * 16 + lm) * 64 + ko * 32 + lq * 8];
        }
        bf16x4 pk[4][4];
        #pragma unroll
        for (int mi = 0; mi < 4; ++mi)
            #pragma unroll
            for (int ci = 0; ci < 4; ++ci)
                #pragma unroll
                for (int reg = 0; reg < 4; ++reg) {
                    float e = __expf(St[mi][ci][reg]);
                    lsum[mi] += e;
                    pk[mi][ci][reg] = (__bf16)e;
                }
        #pragma unroll
        for (int ko = 0; ko < 2; ++ko) {
            bf16x8 af[4];
            #pragma unroll
            for (int mi = 0; mi < 4; ++mi)
                #pragma unroll
                for (int r = 0; r < 4; ++r) {
                    af[mi][r]     = pk[mi][2 * ko][r];
                    af[mi][4 + r] = pk[mi][2 * ko + 1][r];
                }
            #pragma unroll
            for (int ni = 0; ni < 4; ++ni) {
                const __bf16* vrow = &vt[((size_t)bh * 64 + ni * 16 + lm) * 8192 + c0 + ko * 32 + lq * 4];
                bf16x4 v0 = *(const bf16x4*)&vrow[0];
                bf16x4 v1 = *(const bf16x4*)&vrow[16];
                bf16x8 vb;
                #pragma unroll
                for (int r = 0; r < 4; ++r) { vb[r] = v0[r]; vb[4 + r] = v1[r]; }
                #pragma unroll
                for (int mi = 0; mi < 4; ++mi)
                    O[mi][ni] = mfma_bf16(af[mi], vb, O[mi][ni]);
            }
        }
    }
    #pragma unroll
    for (int mi = 0; mi < 4; ++mi) {
        float v = lsum[mi];
        v += __shfl_xor(v, 16);
        v += __shfl_xor(v, 32);
        lsum[mi] = v;
    }
    int base = (bh * 16 + s) * 256;
    #pragma unroll
    for (int mi = 0; mi < 4; ++mi)
        if (lq == 0) l_s[base + wave * 64 + mi * 16 + lm] = lsum[mi];
    #pragma unroll
    for (int mi = 0; mi < 4; ++mi)
        #pragma unroll
        for (int reg = 0; reg < 4; ++reg) {
            int r = wave * 64 + mi * 16 + lq * 4 + reg;
            #pragma unroll
            for (int ni = 0; ni < 4; ++ni)
                O_s[((size_t)(base + r)) * 64 + ni * 16 + lm] = O[mi][ni][reg];
        }
}

// ---- t2combine body ----
__device__ __forceinline__ void t2c_body(int idx, const float* __restrict__ O_s,
        const float* __restrict__ l_s, __bf16* __restrict__ t2th,
        __bf16* __restrict__ t2tl) {
    int bh = idx >> 14, r = (idx >> 6) & 255, d = idx & 63;
    float den = 0.f, num = 0.f;
    #pragma unroll
    for (int s = 0; s < 16; ++s) {
        int b2 = (bh * 16 + s) * 256 + r;
        den += l_s[b2];
        num += O_s[(size_t)b2 * 64 + d];
    }
    float v = num / den;
    __bf16 hh = (__bf16)v;
    size_t di = ((size_t)bh * 64 + d) * 256 + r;   // transposed: [bh][d][r]
    t2th[di] = hh;
    t2tl[di] = (__bf16)(v - (float)hh);
}

// ---- depthwise conv body ----
__device__ __forceinline__ void conv_body(int bxx, int bh,
        const __bf16* __restrict__ vt, const float* __restrict__ resk,
        __bf16* __restrict__ convb, float* kfs) {
    int h = bh & 7;
    int d = threadIdx.x & 63, tg = threadIdx.x >> 6;
    int t0 = bxx * 64 + tg * 16;
    if (threadIdx.x < 33) kfs[threadIdx.x] = resk[h * 33 + threadIdx.x];
    __syncthreads();
    const __bf16* row = vt + ((size_t)bh * 64 + d) * 8192;
    float win[48];
    #pragma unroll
    for (int c = 0; c < 6; ++c) {
        int tok0 = t0 - 16 + c * 8;
        if (tok0 >= 0 && tok0 + 7 < 8192) {
            bf16x8 v8 = *(const bf16x8*)&row[tok0];
            #pragma unroll
            for (int e = 0; e < 8; ++e) win[c * 8 + e] = (float)v8[e];
        } else {
            #pragma unroll
            for (int e = 0; e < 8; ++e) {
                int tok = tok0 + e;
                win[c * 8 + e] = (tok >= 0 && tok < 8192) ? (float)row[tok] : 0.f;
            }
        }
    }
    float o[16];
    #pragma unroll
    for (int i = 0; i < 16; ++i) o[i] = 0.f;
    #pragma unroll
    for (int j = 0; j < 33; ++j) {
        float kf = kfs[j];
        #pragma unroll
        for (int i = 0; i < 16; ++i) o[i] += kf * win[i + j];
    }
    __bf16* outr = convb + ((size_t)bh * 8192) * 64 + d;
    #pragma unroll
    for (int i = 0; i < 16; ++i)
        outr[(size_t)(t0 + i) * 64] = (__bf16)o[i];
}

// ================= kernels =================

// ---- F1: cvt(8192) + transpose(wqkv)(192) + transpose(wout)(64) ----
__global__ __launch_bounds__(256) void k_fuse_pre(const float* __restrict__ x,
        __bf16* __restrict__ xb, float* __restrict__ stats,
        const float* __restrict__ wqkv, __bf16* __restrict__ wqkvt,
        const float* __restrict__ wout, __bf16* __restrict__ woutt) {
    __shared__ __bf16 tile[64 * 72];
    int id = blockIdx.x;
    if (id < 8192) {
        if (id == 0 && threadIdx.x == 0) { stats[0] = 1.f; stats[1] = 0.f; }
        cvt_body(id, x, xb);
    } else if (id < 8384) {
        int lid = id - 8192;
        tf32_body(wqkv, wqkvt, 512, 1536, lid & 7, lid >> 3, tile);
    } else {
        int lid = id - 8384;
        tf32_body(wout, woutt, 512, 512, lid & 7, lid >> 3, tile);
    }
}

// ---- big GEMM: C = A(MxK,bf16) @ Bt(NxK,bf16)^T, 128x128 tile ----
template<int MODE>
__global__ __launch_bounds__(256) void k_gemm_big(const __bf16* __restrict__ A,
        const __bf16* __restrict__ Bt, int K,
        __bf16* __restrict__ qp, __bf16* __restrict__ kp, __bf16* __restrict__ vp,
        float* __restrict__ outp, const float* __restrict__ bias) {
    __shared__ __bf16 sA[128 * 64];
    __shared__ __bf16 sB[128 * 64];
    constexpr int NT  = (MODE == 0) ? 12 : 4;      // n-tiles
    constexpr int TOT = (MODE == 0) ? 3072 : 1024; // total blocks
    int flat = blockIdx.x;
    int t = (flat & 7) * (TOT / 8) + (flat >> 3);
    int m0 = (t / NT) * 128, n0 = (t % NT) * 128;
    int tid = threadIdx.x;
    int wave = tid >> 6, l = tid & 63, lm = l & 15, lq = l >> 4;
    int wm = wave & 1, wn = wave >> 1;
    int lr = l >> 3, lc8 = l & 7;
    int src_c = (lc8 ^ lr) * 8;          // inverse-swizzled source column
    f32x4 acc[4][4] = {};
    for (int k0 = 0; k0 < K; k0 += 64) {
        #pragma unroll
        for (int i = 0; i < 4; ++i) {
            int g = wave * 4 + i;        // 8-row group
            gload16(&A[(size_t)(m0 + g * 8 + lr) * K + k0 + src_c], &sA[g * 512]);
        }
        #pragma unroll
        for (int i = 0; i < 4; ++i) {
            int g = wave * 4 + i;
            gload16(&Bt[(size_t)(n0 + g * 8 + lr) * K + k0 + src_c], &sB[g * 512]);
        }
        __syncthreads();
        #pragma unroll
        for (int ko = 0; ko < 2; ++ko) {
            int ch = (ko << 2) | lq;     // chunk index 0..7
            bf16x8 af[4], bfr[4];
            #pragma unroll
            for (int mi = 0; mi < 4; ++mi) {
                int r = wm * 64 + mi * 16 + lm;
                af[mi] = *(bf16x8*)&sA[r * 64 + ((ch ^ (r & 7)) << 3)];
            }
            #pragma unroll
            for (int ni = 0; ni < 4; ++ni) {
                int r = wn * 64 + ni * 16 + lm;
                bfr[ni] = *(bf16x8*)&sB[r * 64 + ((ch ^ (r & 7)) << 3)];
            }
            #pragma unroll
            for (int mi = 0; mi < 4; ++mi)
                #pragma unroll
                for (int ni = 0; ni < 4; ++ni)
                    acc[mi][ni] = mfma_bf16(af[mi], bfr[ni], acc[mi][ni]);
        }
        __syncthreads();
    }
    #pragma unroll
    for (int mi = 0; mi < 4; ++mi)
    #pragma unroll
    for (int ni = 0; ni < 4; ++ni)
    #pragma unroll
    for (int reg = 0; reg < 4; ++reg) {
        int gr = m0 + wm * 64 + mi * 16 + lq * 4 + reg;
        int gc = n0 + wn * 64 + ni * 16 + lm;
        float v = acc[mi][ni][reg];
        if (MODE == 0) {
            int which = gc >> 9, rem = gc & 511;
            int h = rem >> 6, d = rem & 63;
            int b = gr >> 13, tok = gr & 8191;
            size_t dst = ((size_t)((b * 8 + h) * 8192 + tok)) * 64 + d;
            if (which == 0)      qp[dst] = (__bf16)(v * 0.125f);
            else if (which == 1) kp[dst] = (__bf16)v;
            else                 vp[dst] = (__bf16)v;
        } else {
            outp[(size_t)gr * 512 + gc] = v + bias[gc];
        }
    }
}

// ---- F2: v-transpose(4096) + landmarks(4096) ----
__global__ __launch_bounds__(256) void k_fuse_tl(const __bf16* __restrict__ vsrc,
        __bf16* __restrict__ vt, const __bf16* __restrict__ q,
        const __bf16* __restrict__ k, __bf16* __restrict__ ql,
        __bf16* __restrict__ kl) {
    __shared__ __bf16 tile[64 * 72];
    int id = blockIdx.x;
    if (id < 4096) {
        tbf_body(vsrc, vt, id & 127, id >> 7, tile);
    } else {
        landmarks_body((id - 4096) * 256 + threadIdx.x, q, k, ql, kl);
    }
}

// ---- attn2 = softmax(q_l @ k_l^T), hi/lo bf16 planes ----
__global__ __launch_bounds__(256) void k_attn2(const __bf16* __restrict__ ql,
        const __bf16* __restrict__ kl, __bf16* __restrict__ ph, __bf16* __restrict__ pl) {
    int tid = threadIdx.x;
    int wave = tid >> 6, l = tid & 63, lm = l & 15, lq = l >> 4;
    int bh = blockIdx.y;
    int r0 = blockIdx.x * 64 + wave * 16;
    const __bf16* qb = ql + (size_t)bh * 16384;
    const __bf16* kb = kl + (size_t)bh * 16384;
    bf16x8 af[2];
    #pragma unroll
    for (int ko = 0; ko < 2; ++ko)
        af[ko] = *(const bf16x8*)&qb[(size_t)(r0 + lm) * 64 + ko * 32 + lq * 8];
    f32x4 S[16] = {};
    #pragma unroll
    for (int ci = 0; ci < 16; ++ci)
        #pragma unroll
        for (int ko = 0; ko < 2; ++ko) {
            bf16x8 bfr = *(const bf16x8*)&kb[(size_t)(ci * 16 + lm) * 64 + ko * 32 + lq * 8];
            S[ci] = mfma_bf16(af[ko], bfr, S[ci]);
        }
    __bf16* oh = ph + (size_t)bh * 65536;
    __bf16* ol = pl + (size_t)bh * 65536;
    #pragma unroll
    for (int reg = 0; reg < 4; ++reg) {
        float sum = 0.f;
        #pragma unroll
        for (int ci = 0; ci < 16; ++ci) {
            float e = __expf(S[ci][reg]); S[ci][reg] = e; sum += e;
        }
        #pragma unroll
        for (int msk = 1; msk < 16; msk <<= 1) sum += __shfl_xor(sum, msk);
        float inv = 1.f / sum;
        int row = r0 + lq * 4 + reg;
        #pragma unroll
        for (int ci = 0; ci < 16; ++ci) {
            float v = S[ci][reg] * inv;
            __bf16 hh = (__bf16)v;
            oh[(size_t)row * 256 + ci * 16 + lm] = hh;
            ol[(size_t)row * 256 + ci * 16 + lm] = (__bf16)(v - (float)hh);
        }
    }
}

// ---- max col-sum of attn2 (row-sums are exactly 1) ----
__global__ __launch_bounds__(256) void k_stats(const __bf16* __restrict__ ph,
        const __bf16* __restrict__ pl, float* stats) {
    __shared__ float red[256];
    int tid = threadIdx.x;
    const __bf16* a = ph + (size_t)blockIdx.x * 65536;
    const __bf16* b = pl + (size_t)blockIdx.x * 65536;
    float cs = 0.f;
    for (int r = 0; r < 256; ++r)
        cs += (float)a[r * 256 + tid] + (float)b[r * 256 + tid];
    red[tid] = cs; __syncthreads();
    for (int off = 128; off > 0; off >>= 1) {
        if (tid < off) red[tid] = fmaxf(red[tid], red[tid + off]);
        __syncthreads();
    }
    if (tid == 0) atomicMax((int*)&stats[1], __float_as_int(red[0]));
}

// ---- F3: attn3(512) + z0t(512) + A0(1024)  [conv NOT here: convb aliases O_s] ----
__global__ __launch_bounds__(256) void k_fuse_mid(
        const __bf16* __restrict__ ql, const __bf16* __restrict__ kbf,
        const __bf16* __restrict__ vt, float* __restrict__ O_s,
        float* __restrict__ l_s, const __bf16* __restrict__ a2h,
        const __bf16* __restrict__ a2l, const float* __restrict__ stats,
        __bf16* __restrict__ zAh, __bf16* __restrict__ zAl,
        __bf16* __restrict__ Amh, __bf16* __restrict__ Aml) {
    __shared__ __attribute__((aligned(16))) char smem[24576];
    int id = blockIdx.x;
    if (id < 512) {
        attn3_body(id & 15, id >> 4, ql, kbf, vt, O_s, l_s);
    } else if (id < 1024) {
        __bf16* th = (__bf16*)smem;
        __bf16* tl = (__bf16*)(smem + 8320);    // 64*65*2 = 8320 B per plane
        z0t_body(id - 512, a2h, a2l, stats, zAh, zAl, th, tl);
    } else {
        __bf16* sAh = (__bf16*)smem;
        __bf16* sAl = (__bf16*)(smem + 4096);
        __bf16* sBh = (__bf16*)(smem + 8192);
        __bf16* sBl = (__bf16*)(smem + 16384);
        float sc = 1.f / (stats[0] * stats[1]);
        pgemm_stage(id - 1024, 1024, a2h, a2l, a2h, a2l, nullptr, nullptr,
                    Amh, Aml, sc, 0.f, 0.f, 0, 65536, sAh, sAl, sBh, sBl);
    }
}

// ---- F4: W2_0(1024) + t2combine(2048)  [t2combine drains O_s here] ----
__global__ __launch_bounds__(256) void k_fuse_w2t2(
        const __bf16* __restrict__ Amh, const __bf16* __restrict__ Aml,
        __bf16* __restrict__ W2h, __bf16* __restrict__ W2l,
        const float* __restrict__ O_s, const float* __restrict__ l_s,
        __bf16* __restrict__ t2th, __bf16* __restrict__ t2tl) {
    __shared__ __bf16 sAh[32 * 64], sAl[32 * 64], sBh[64 * 64], sBl[64 * 64];
    int id = blockIdx.x;
    if (id < 1024) {
        pgemm_stage(id, 1024, Amh, Aml, Amh, Aml, Amh, Aml, W2h, W2l,
                    1.f, -7.f, 15.f, 0, 65536, sAh, sAl, sBh, sBl);
    } else {
        t2c_body((id - 1024) * 256 + threadIdx.x, O_s, l_s, t2th, t2tl);
    }
}

// ---- F5: W3_0(1024) + conv(4096)  [conv safe: O_s drained by F4] ----
__global__ __launch_bounds__(256) void k_fuse_w3conv(
        const __bf16* __restrict__ Amh, const __bf16* __restrict__ Aml,
        const __bf16* __restrict__ W2h, const __bf16* __restrict__ W2l,
        __bf16* __restrict__ W3h, __bf16* __restrict__ W3l,
        const __bf16* __restrict__ vt, const float* __restrict__ resk,
        __bf16* __restrict__ convb) {
    __shared__ __bf16 sAh[32 * 64], sAl[32 * 64], sBh[64 * 64], sBl[64 * 64];
    __shared__ float kfs[33];
    int id = blockIdx.x;
    if (id < 1024) {
        pgemm_stage(id, 1024, Amh, Aml, W2h, W2l, nullptr, nullptr, W3h, W3l,
                    -1.f, 0.f, 13.f, 0, 65536, sAh, sAl, sBh, sBl);
    } else {
        int lid = id - 1024;
        conv_body(lid & 127, lid >> 7, vt, resk, convb, kfs);
    }
}

// ---- standalone chain stage ----
__global__ __launch_bounds__(256) void k_pgemm(const __bf16* __restrict__ Ah,
        const __bf16* __restrict__ Al, const __bf16* __restrict__ Bth,
        const __bf16* __restrict__ Btl, const __bf16* __restrict__ Ch,
        const __bf16* __restrict__ Cl, __bf16* __restrict__ OutH,
        __bf16* __restrict__ OutL, float alpha, const float* __restrict__ sPtr,
        float beta, float delta, int outMode, long bStride) {
    __shared__ __bf16 sAh[32 * 64], sAl[32 * 64], sBh[64 * 64], sBl[64 * 64];
    float aEff = alpha;
    if (sPtr) aEff *= 1.f / (sPtr[0] * sPtr[1]);
    pgemm_stage(blockIdx.x, gridDim.x, Ah, Al, Bth, Btl, Ch, Cl, OutH, OutL,
                aEff, beta, delta, outMode, bStride, sAh, sAl, sBh, sBl);
}

// ---- dual update: z' = 0.25 z@W3 (zz<32), A' = 0.25 A@W3 (zz>=32) ----
__global__ __launch_bounds__(256) void k_pgemm_dual(const __bf16* __restrict__ Zh,
        const __bf16* __restrict__ Zl, const __bf16* __restrict__ A2h,
        const __bf16* __restrict__ A2l, const __bf16* __restrict__ Bth,
        const __bf16* __restrict__ Btl, __bf16* __restrict__ OzH,
        __bf16* __restrict__ OzL, __bf16* __restrict__ OaH, __bf16* __restrict__ OaL) {
    __shared__ __bf16 sAh[32 * 64], sAl[32 * 64], sBh[64 * 64], sBl[64 * 64];
    int tid = threadIdx.x;
    int wave = tid >> 6, l = tid & 63, lm = l & 15, lq = l >> 4;
    int wm = wave & 1, wn = wave >> 1;
    int total = gridDim.x;
    int flat = blockIdx.x;
    int t = (flat & 7) * (total >> 3) + (flat >> 3);
    int zz = t >> 5, rem = t & 31;
    int m0 = (rem >> 2) * 32, n0 = (rem & 3) * 64;
    int bh = zz & 31;
    const __bf16* Lh = (zz >= 32 ? A2h : Zh) + (size_t)bh * 65536;
    const __bf16* Ll = (zz >= 32 ? A2l : Zl) + (size_t)bh * 65536;
    __bf16* Oh = (zz >= 32 ? OaH : OzH) + (size_t)bh * 65536;
    __bf16* Ol = (zz >= 32 ? OaL : OzL) + (size_t)bh * 65536;
    f32x4 acc[2] = {};
    pgemm_core(Lh, Ll, Bth + (size_t)bh * 65536, Btl + (size_t)bh * 65536,
               m0, n0, sAh, sAl, sBh, sBl, acc);
    #pragma unroll
    for (int ni = 0; ni < 2; ++ni)
    #pragma unroll
    for (int reg = 0; reg < 4; ++reg) {
        int gr = m0 + wm * 16 + lq * 4 + reg;
        int gc = n0 + wn * 32 + ni * 16 + lm;
        float v = 0.25f * acc[ni][reg];
        __bf16 hh = (__bf16)v;
        Oh[(size_t)gr * 256 + gc] = hh;
        Ol[(size_t)gr * 256 + gc] = (__bf16)(v - (float)hh);
    }
}

// ---- attn1 fused: softmax(q k_l^T) @ zt2 + convb (64 rows/wave, zero LDS) ----
__global__ __launch_bounds__(256) void k_attn1(const __bf16* __restrict__ q,
        const __bf16* __restrict__ kl, const __bf16* __restrict__ zt2p,
        const __bf16* __restrict__ convb, __bf16* __restrict__ outp) {
    int tid = threadIdx.x;
    int wave = tid >> 6, l = tid & 63, lm = l & 15, lq = l >> 4;
    int bh = blockIdx.y;
    int t0 = blockIdx.x * 256;
    int b = bh >> 3, h = bh & 7;
    const __bf16* qb = q + (size_t)bh * 8192 * 64;
    const __bf16* kb = kl + (size_t)bh * 16384;
    const __bf16* zb = zt2p + (size_t)bh * 16384;
    int rowb = t0 + wave * 64;
    bf16x8 qa[4][2];
    #pragma unroll
    for (int mi = 0; mi < 4; ++mi)
        #pragma unroll
        for (int ko = 0; ko < 2; ++ko)
            qa[mi][ko] = *(const bf16x8*)&qb[(size_t)(rowb + mi * 16 + lm) * 64 + ko * 32 + lq * 8];
    f32x4 O[4][4] = {};
    float rs[4] = {};
    #pragma unroll
    for (int c2 = 0; c2 < 8; ++c2) {       // 2 landmark-col blocks per chunk
        bf16x8 kf[2][2];
        #pragma unroll
        for (int ci = 0; ci < 2; ++ci)
            #pragma unroll
            for (int ko = 0; ko < 2; ++ko)
                kf[ci][ko] = *(const bf16x8*)&kb[(size_t)((c2 * 2 + ci) * 16 + lm) * 64 + ko * 32 + lq * 8];
        f32x4 St[4][2] = {};
        #pragma unroll
        for (int ci = 0; ci < 2; ++ci)
            #pragma unroll
            for (int ko = 0; ko < 2; ++ko)
                #pragma unroll
                for (int mi = 0; mi < 4; ++mi)
                    St[mi][ci] = mfma_bf16(kf[ci][ko], qa[mi][ko], St[mi][ci]);
        bf16x4 pk[4][2];
        #pragma unroll
        for (int mi = 0; mi < 4; ++mi)
            #pragma unroll
            for (int ci = 0; ci < 2; ++ci)
                #pragma unroll
                for (int reg = 0; reg < 4; ++reg) {
                    float e = __expf(St[mi][ci][reg]);
                    rs[mi] += e;
                    pk[mi][ci][reg] = (__bf16)e;
                }
        bf16x8 zfr[4];
        #pragma unroll
        for (int ni = 0; ni < 4; ++ni)
            zfr[ni] = *(const bf16x8*)&zb[(size_t)(ni * 16 + lm) * 256 + c2 * 32 + lq * 8];
        #pragma unroll
        for (int mi = 0; mi < 4; ++mi) {
            bf16x8 af;
            #pragma unroll
            for (int r = 0; r < 4; ++r) {
                af[r]     = pk[mi][0][r];
                af[4 + r] = pk[mi][1][r];
            }
            #pragma unroll
            for (int ni = 0; ni < 4; ++ni)
                O[mi][ni] = mfma_bf16(af, zfr[ni], O[mi][ni]);
        }
    }
    #pragma unroll
    for (int mi = 0; mi < 4; ++mi) {
        float v = rs[mi];
        v += __shfl_xor(v, 16);
        v += __shfl_xor(v, 32);            // rowsum(rowb+mi*16+lm) on all lq-copies
        float invr[4];
        #pragma unroll
        for (int reg = 0; reg < 4; ++reg)
            invr[reg] = 1.f / __shfl(v, lq * 4 + reg);
        #pragma unroll
        for (int ni = 0; ni < 4; ++ni)
            #pragma unroll
            for (int reg = 0; reg < 4; ++reg) {
                int tok = rowb + mi * 16 + lq * 4 + reg;
                int d = ni * 16 + lm;
                float conv = (float)convb[((size_t)bh * 8192 + tok) * 64 + d];
                float val = O[mi][ni][reg] * invr[reg] + conv;
                outp[((size_t)(b * 8192 + tok)) * 512 + h * 64 + d] = (__bf16)val;
            }
    }
}

// ---------------- launcher ----------------
extern "C" void kernel_launch(void* const* d_in, const int* in_sizes, int n_in,
                              void* d_out, int out_size, void* d_ws, size_t ws_size,
                              hipStream_t stream) {
    const float* x    = (const float*)d_in[0];
    const float* wqkv = (const float*)d_in[1];
    const float* wout = (const float*)d_in[2];
    const float* bout = (const float*)d_in[3];
    const float* resk = (const float*)d_in[4];
    char* ws = (char*)d_ws;
    size_t off = 0;
    auto alloc = [&](size_t bytes) {
        char* p = ws + off;
        off += (bytes + 255) & ~(size_t)255;
        return p;
    };
    const size_t PL = 2097152;                   // elems per 4MB bf16 plane (32x256x256)
    __bf16* q_bf   = (__bf16*)alloc(33554432);   // (bh,n,d)
    __bf16* k_bf   = (__bf16*)alloc(33554432);   // (bh,n,d)
    __bf16* vt     = (__bf16*)alloc(33554432);   // (bh,d,n)
    __bf16* outpre = (__bf16*)alloc(33554432);   // v_tmp early, attn1 out later
    __bf16* q_l    = (__bf16*)alloc(1048576);
    __bf16* k_l    = (__bf16*)alloc(1048576);
    __bf16* a2h    = (__bf16*)alloc(8388608);    // attn2 hi/lo planes; An slot later
    __bf16* zAh    = (__bf16*)alloc(8388608);
    __bf16* zBh    = (__bf16*)alloc(8388608);
    __bf16* Amh    = (__bf16*)alloc(8388608);
    __bf16* W2h    = (__bf16*)alloc(8388608);
    __bf16* W3h    = (__bf16*)alloc(8388608);
    float*  O_s    = (float*)alloc(33554432);    // xb early, attn3 out, convb late
    float*  l_s    = (float*)alloc(524288);
    __bf16* t2th   = (__bf16*)alloc(2097152);    // t2^T hi/lo planes (1MB each)
    __bf16* zt2t   = (__bf16*)alloc(1048576);
    __bf16* wqkvt  = (__bf16*)alloc(1572864);
    __bf16* woutt  = (__bf16*)alloc(524288);
    float*  stats  = (float*)alloc(256);
    __bf16* convb  = (__bf16*)O_s;               // alias (32 MB <= 33.5 MB)
    __bf16* xb     = (__bf16*)O_s;               // alias: x bf16, dead before attn3
    __bf16* a2l = a2h + PL;
    __bf16* zAl = zAh + PL;
    __bf16* zBl = zBh + PL;
    __bf16* Aml = Amh + PL;
    __bf16* W2l = W2h + PL;
    __bf16* W3l = W3h + PL;
    __bf16* t2tl = t2th + 524288;

    // F1: cvt + weight transposes (+ stats init)
    k_fuse_pre<<<8448, 256, 0, stream>>>(x, xb, stats, wqkv, wqkvt, wout, woutt);
    k_gemm_big<0><<<3072, 256, 0, stream>>>(xb, wqkvt, 512,
            q_bf, k_bf, outpre, nullptr, nullptr);
    // F2: v-transpose + landmarks
    k_fuse_tl<<<8192, 256, 0, stream>>>(outpre, vt, q_bf, k_bf, q_l, k_l);
    k_attn2<<<dim3(4, 32), 256, 0, stream>>>(q_l, k_l, a2h, a2l);
    k_stats<<<32, 256, 0, stream>>>(a2h, a2l, stats);
    // F3: attn3 + z0t + A0 (conv excluded: convb aliases O_s)
    k_fuse_mid<<<2048, 256, 0, stream>>>(q_l, k_bf, vt, O_s, l_s,
            a2h, a2l, stats, zAh, zAl, Amh, Aml);
    // F4: W2_0 + t2combine (consumes O_s)
    k_fuse_w2t2<<<3072, 256, 0, stream>>>(Amh, Aml, W2h, W2l, O_s, l_s, t2th, t2tl);
    // F5: W3_0 + conv (O_s now dead -> convb reuse safe)
    k_fuse_w3conv<<<5120, 256, 0, stream>>>(Amh, Aml, W2h, W2l, W3h, W3l,
            vt, resk, convb);

    __bf16 *zch = zAh, *zcl = zAl, *znh = zBh, *znl = zBl;
    __bf16 *Ach = Amh, *Acl = Aml, *Anh = a2h, *Anl = a2l;   // attn2 planes dead after A0
    for (int it = 0; it < 6; ++it) {
        if (it > 0) {
            k_pgemm<<<1024, 256, 0, stream>>>(Ach, Acl, Ach, Acl,
                    Ach, Acl, W2h, W2l, 1.f, nullptr, -7.f, 15.f, 0, 65536); // W2 = 15I - 7A + A@A
            k_pgemm<<<1024, 256, 0, stream>>>(Ach, Acl, W2h, W2l,
                    nullptr, nullptr, W3h, W3l, -1.f, nullptr, 0.f, 13.f, 0, 65536); // W3 = 13I - A@W2
        }
        if (it < 5) {
            k_pgemm_dual<<<2048, 256, 0, stream>>>(zch, zcl, Ach, Acl,
                    W3h, W3l, znh, znl, Anh, Anl);
            __bf16* t;
            t = Ach; Ach = Anh; Anh = t;
            t = Acl; Acl = Anl; Anl = t;
        } else {
            k_pgemm_dual<<<1024, 256, 0, stream>>>(zch, zcl, zch, zcl,
                    W3h, W3l, znh, znl, znh, znl);
        }
        __bf16* t;
        t = zch; zch = znh; znh = t;
        t = zcl; zcl = znl; znl = t;
    }
    // zt2t[bh][d][slot] = (z_final @ t2)^T, bf16, slot-permuted for attn1's PV
    k_pgemm<<<256, 256, 0, stream>>>(zch, zcl, t2th, t2tl,
            nullptr, nullptr, zt2t, nullptr, 1.f, nullptr, 0.f, 0.f, 1, 16384);
    k_attn1<<<dim3(32, 32), 256, 0, stream>>>(q_bf, k_l, zt2t, convb, outpre);
    k_gemm_big<1><<<1024, 256, 0, stream>>>(outpre, woutt, 512,
            nullptr, nullptr, nullptr, (float*)d_out, bout);
}